// Round 6
// baseline (300.204 us; speedup 1.0000x reference)
//
#include <hip/hip_runtime.h>
#include <hip/hip_cooperative_groups.h>

namespace cg = cooperative_groups;

#define EPS 1e-3f
#define Bn 16
#define Tn 2048
#define Dn 256
#define Kn 8

// ---- cooperative fused geometry ----
#define TS1 64                       // t-chunks per batch row (phase A/C)
#define TCH 32                       // Tn / TS1
#define GRID_F 1024                  // TS1 * Bn = 64*16 blocks (4/CU)
#define KBD ((size_t)Kn * Bn * Dn)   // 32768
#define KD  (Kn * Dn)                // 2048

// ---- fallback (multi-kernel) geometry ----
#define TS2 128
#define TCH2 (Tn / TS2)
#define NG 4

__device__ __forceinline__ float fexp2(float x) {
#if __has_builtin(__builtin_amdgcn_exp2f)
    return __builtin_amdgcn_exp2f(x);
#else
    return exp2f(x);
#endif
}
__device__ __forceinline__ float frcp(float x) {
#if __has_builtin(__builtin_amdgcn_rcpf)
    return __builtin_amdgcn_rcpf(x);
#else
    return 1.0f / x;
#endif
}

// exp(-0.5 (x-m)^2/(softplus(v)+eps)) = exp2(A x^2 + B x + G)
__device__ __forceinline__ void load_coefs(
    const float* __restrict__ Mean, const float* __restrict__ Var, int d,
    float* Ak, float* Bk, float* Gk)
{
    const float L2E = 1.4426950408889634f;
#pragma unroll
    for (int k = 0; k < Kn; ++k) {
        float m  = Mean[k * Dn + d];
        float v  = Var[k * Dn + d];
        float sp = logf(1.0f + expf(v));          // softplus
        float c2 = -0.5f * L2E / (sp + EPS);
        Ak[k] = c2;
        Bk[k] = -2.0f * c2 * m;
        Gk[k] = c2 * m * m;
    }
}

// ======================= cooperative fused kernel =======================
// ws: P[3][TS1][KBD] | Q[3][KBD] | S[KD]
__global__ __launch_bounds__(256, 4) void ucb_fused(
    const float* __restrict__ X,
    const float* __restrict__ Mean, const float* __restrict__ Var,
    float* __restrict__ WS, float* __restrict__ Out)
{
    float* P = WS;                          // 3*TS1*KBD
    float* Q = WS + 3 * TS1 * KBD;          // 3*KBD
    float* S = Q + 3 * KBD;                 // KD

    const int tid = threadIdx.x;            // = d
    const int bid = blockIdx.x;             // 0..1023
    const int tc  = bid & (TS1 - 1);
    const int b   = bid >> 6;
    const int d   = tid;

    float Ak[Kn], Bk[Kn], Gk[Kn];
    load_coefs(Mean, Var, d, Ak, Bk, Gk);

    if (bid == 0) {                         // zero S for this call's atomics
#pragma unroll
        for (int i = 0; i < KD / 256; ++i) S[i * 256 + tid] = 0.f;
    }

    // ---- Phase A: per-block partials (plain stores, no atomics) ----
    const float* xp = X + ((size_t)b * Tn + (size_t)tc * TCH) * Dn + d;

    float s0[Kn], s1[Kn], s3[Kn];
#pragma unroll
    for (int k = 0; k < Kn; ++k) { s0[k] = 0.f; s1[k] = 0.f; s3[k] = 0.f; }

#pragma unroll 4
    for (int t = 0; t < TCH; ++t) {
        float xv = xp[(size_t)t * Dn];
        float p[Kn];
        float sum = EPS;
#pragma unroll
        for (int k = 0; k < Kn; ++k) {
            float arg = fmaf(fmaf(Ak[k], xv, Bk[k]), xv, Gk[k]);
            p[k] = fexp2(arg);
            sum += p[k];
        }
        float q    = frcp(sum);
        float xq   = xv * q;
        float q2   = q * q;
        float xxq3 = (xv * xv) * (q2 * q);
#pragma unroll
        for (int k = 0; k < Kn; ++k) {
            float pk = p[k];
            float p3 = pk * pk * pk;
            s0[k] = fmaf(pk, q,    s0[k]);
            s1[k] = fmaf(pk, xq,   s1[k]);
            s3[k] = fmaf(p3, xxq3, s3[k]);
        }
    }

#pragma unroll
    for (int k = 0; k < Kn; ++k) {
        size_t o = (size_t)tc * KBD + ((size_t)(k * Bn + b) << 8) + d;
        P[o] = s0[k];
        P[TS1 * KBD + o] = s1[k];
        P[2 * TS1 * KBD + o] = s3[k];
    }

    cg::this_grid().sync();

    // ---- Phase B: reduce over tc (blocks 0..383); arr 0 b-sums into S ----
    if (bid < 3 * (int)(KBD / 256)) {
        size_t idx = (size_t)bid * 256 + tid;       // 0..98303
        int    arr = (int)(idx >> 15);              // / KBD
        size_t rem = idx & (KBD - 1);
        const float* pp = P + (size_t)arr * TS1 * KBD + rem;
        float a = 0.f;
#pragma unroll 8
        for (int t = 0; t < TS1; ++t) a += pp[(size_t)t * KBD];
        Q[(size_t)arr * KBD + rem] = a;
        if (arr == 0) {
            int kk = (int)(rem >> 12);
            int dd = (int)(rem & (Dn - 1));
            atomicAdd(&S[kk * Dn + dd], a);         // 32K atomics, 16-way contention
        }
    }

    cg::this_grid().sync();

    // ---- Phase C: per-thread R/E prologue, then output (X re-read, L2/L3 hit) ----
    const float rs = rsqrtf(1.0f + EPS);            // 1/sqrt(pri+eps), pri==1
    float Rk[Kn], Ek[Kn];
#pragma unroll
    for (int k = 0; k < Kn; ++k) {
        float s  = S[k * Dn + d] + EPS;
        float iS = frcp(s);
        size_t idx = ((size_t)(k * Bn + b) << 8) + d;
        float a1 = Q[KBD + idx];
        float a3 = Q[2 * KBD + idx];
        float E  = a1 * iS * (1.0f / Tn);
        float V  = a3 * (iS * iS * iS) * (1.0f / Tn);
        float r  = rs * rsqrtf(V + EPS);
        Rk[k] = r;
        Ek[k] = r * E;
    }

    float* op = Out + ((size_t)b * Tn + (size_t)tc * TCH) * Dn + d;
#pragma unroll 4
    for (int t = 0; t < TCH; ++t) {
        float xv  = xp[(size_t)t * Dn];
        float sum = EPS;
        float acc = 0.f;
#pragma unroll
        for (int k = 0; k < Kn; ++k) {
            float arg = fmaf(fmaf(Ak[k], xv, Bk[k]), xv, Gk[k]);
            float pv  = fexp2(arg);
            sum += pv;
            acc = fmaf(pv, fmaf(Rk[k], xv, -Ek[k]), acc);
        }
        op[(size_t)t * Dn] = acc * frcp(sum);
    }
}

// ======================= fallback multi-kernel path =======================
__global__ __launch_bounds__(256) void ucb_pass1(
    const float* __restrict__ X,
    const float* __restrict__ Mean, const float* __restrict__ Var,
    float* __restrict__ P0, float* __restrict__ P1, float* __restrict__ P3,
    int tch)
{
    const int d  = threadIdx.x;
    const int tc = blockIdx.x;
    const int b  = blockIdx.y;

    float Ak[Kn], Bk[Kn], Gk[Kn];
    load_coefs(Mean, Var, d, Ak, Bk, Gk);

    float s0[Kn], s1[Kn], s3[Kn];
#pragma unroll
    for (int k = 0; k < Kn; ++k) { s0[k] = 0.f; s1[k] = 0.f; s3[k] = 0.f; }

    const float* xp = X + ((size_t)b * Tn + (size_t)tc * tch) * Dn + d;
#pragma unroll 4
    for (int t = 0; t < tch; ++t) {
        float xv = xp[(size_t)t * Dn];
        float p[Kn];
        float sum = EPS;
#pragma unroll
        for (int k = 0; k < Kn; ++k) {
            float arg = fmaf(fmaf(Ak[k], xv, Bk[k]), xv, Gk[k]);
            p[k] = fexp2(arg);
            sum += p[k];
        }
        float q    = frcp(sum);
        float xq   = xv * q;
        float q2   = q * q;
        float xxq3 = (xv * xv) * (q2 * q);
#pragma unroll
        for (int k = 0; k < Kn; ++k) {
            float pk = p[k];
            float p3 = pk * pk * pk;
            s0[k] = fmaf(pk, q,    s0[k]);
            s1[k] = fmaf(pk, xq,   s1[k]);
            s3[k] = fmaf(p3, xxq3, s3[k]);
        }
    }

#pragma unroll
    for (int k = 0; k < Kn; ++k) {
        size_t o = (size_t)tc * KBD + ((size_t)(k * Bn + b) << 8) + d;
        P0[o] = s0[k];
        P1[o] = s1[k];
        P3[o] = s3[k];
    }
}

__global__ __launch_bounds__(256) void ucb_reduceA(
    const float* __restrict__ P, float* __restrict__ Q, int ts1)
{
    const size_t idx = (size_t)blockIdx.x * 256 + threadIdx.x;
    const int arr = blockIdx.y;
    const int g   = blockIdx.z;
    const int per = ts1 / NG;

    const float* p = P + ((size_t)arr * ts1 + (size_t)g * per) * KBD + idx;
    float a = 0.f;
#pragma unroll 4
    for (int i = 0; i < per; ++i)
        a += p[(size_t)i * KBD];
    Q[((size_t)(arr * NG + g)) * KBD + idx] = a;
}

__global__ __launch_bounds__(256) void ucb_mid(
    const float* __restrict__ Q,
    float* __restrict__ R, float* __restrict__ RE)
{
    const size_t idx = (size_t)blockIdx.x * 256 + threadIdx.x;
    const int k = (int)(idx >> 12);
    const int d = (int)(idx & (Dn - 1));

    float s = EPS;
#pragma unroll
    for (int g = 0; g < NG; ++g) {
        const float* q0 = Q + (size_t)g * KBD + ((size_t)k << 12) + d;
#pragma unroll
        for (int b2 = 0; b2 < Bn; ++b2)
            s += q0[(size_t)b2 << 8];
    }
    float iS = frcp(s);

    float a1 = 0.f, a3 = 0.f;
#pragma unroll
    for (int g = 0; g < NG; ++g) {
        a1 += Q[((size_t)(NG + g))     * KBD + idx];
        a3 += Q[((size_t)(2 * NG + g)) * KBD + idx];
    }

    const float rs = rsqrtf(1.0f + EPS);
    float E  = a1 * iS * (1.0f / Tn);
    float V  = a3 * iS * iS * iS * (1.0f / Tn);
    float r  = rs * rsqrtf(V + EPS);
    R[idx]  = r;
    RE[idx] = r * E;
}

__global__ __launch_bounds__(256) void ucb_pass2(
    const float* __restrict__ X,
    const float* __restrict__ Mean, const float* __restrict__ Var,
    const float* __restrict__ R, const float* __restrict__ RE,
    float* __restrict__ Out)
{
    const int d  = threadIdx.x;
    const int tc = blockIdx.x;
    const int b  = blockIdx.y;

    float Ak[Kn], Bk[Kn], Gk[Kn];
    load_coefs(Mean, Var, d, Ak, Bk, Gk);

    float Rk[Kn], REk[Kn];
#pragma unroll
    for (int k = 0; k < Kn; ++k) {
        size_t idx = ((size_t)k * Bn + b) * Dn + d;
        Rk[k]  = R[idx];
        REk[k] = RE[idx];
    }

    const size_t base = ((size_t)b * Tn + (size_t)tc * TCH2) * Dn + d;
#pragma unroll 4
    for (int t = 0; t < TCH2; ++t) {
        float xv = X[base + (size_t)t * Dn];
        float p[Kn];
        float sum = EPS;
#pragma unroll
        for (int k = 0; k < Kn; ++k) {
            float arg = fmaf(fmaf(Ak[k], xv, Bk[k]), xv, Gk[k]);
            p[k] = fexp2(arg);
            sum += p[k];
        }
        float inv = frcp(sum);
        float acc = 0.f;
#pragma unroll
        for (int k = 0; k < Kn; ++k) {
            acc = fmaf(p[k], fmaf(Rk[k], xv, -REk[k]), acc);
        }
        Out[base + (size_t)t * Dn] = acc * inv;
    }
}

static void launch_fallback(const float* x, const float* mean, const float* var,
                            float* out, void* d_ws, size_t ws_size,
                            hipStream_t stream)
{
    int ts1 = 64;
    while (ts1 > NG) {
        size_t need = (3 * (size_t)ts1 * KBD + 3 * NG * KBD + 2 * KBD) * sizeof(float);
        if (need <= ws_size) break;
        ts1 >>= 1;
    }
    const int tch1 = Tn / ts1;

    float* P0 = (float*)d_ws;
    float* P1 = P0 + (size_t)ts1 * KBD;
    float* P3 = P1 + (size_t)ts1 * KBD;
    float* Q  = P3 + (size_t)ts1 * KBD;
    float* R  = Q  + 3 * NG * KBD;
    float* RE = R  + KBD;

    ucb_pass1<<<dim3(ts1, Bn), dim3(256), 0, stream>>>(x, mean, var, P0, P1, P3, tch1);
    ucb_reduceA<<<dim3(KBD / 256, 3, NG), dim3(256), 0, stream>>>(P0, Q, ts1);
    ucb_mid<<<dim3(KBD / 256), dim3(256), 0, stream>>>(Q, R, RE);
    ucb_pass2<<<dim3(TS2, Bn), dim3(256), 0, stream>>>(x, mean, var, R, RE, out);
}

extern "C" void kernel_launch(void* const* d_in, const int* in_sizes, int n_in,
                              void* d_out, int out_size, void* d_ws, size_t ws_size,
                              hipStream_t stream)
{
    const float* x    = (const float*)d_in[0];
    const float* mean = (const float*)d_in[1];
    const float* var  = (const float*)d_in[2];
    // d_in[3] (prior): softmax over singleton axis == 1 -> compile-time rsqrt(1+eps)

    const size_t need_fused = (3 * (size_t)TS1 * KBD + 3 * KBD + KD) * sizeof(float);

    if (ws_size >= need_fused) {
        float* ws  = (float*)d_ws;
        float* out = (float*)d_out;
        void* args[] = {(void*)&x, (void*)&mean, (void*)&var, (void*)&ws, (void*)&out};
        hipError_t err = hipLaunchCooperativeKernel((const void*)ucb_fused,
                                                    dim3(GRID_F), dim3(256),
                                                    args, 0, stream);
        if (err == hipSuccess) return;
        // fall through to multi-kernel path if cooperative launch is refused
    }

    launch_fallback(x, mean, var, (float*)d_out, d_ws, ws_size, stream);
}

// Round 7
// 94.978 us; speedup vs baseline: 3.1608x; 3.1608x over previous
//
#include <hip/hip_runtime.h>

#define EPS 1e-3f
#define Bn 16
#define Tn 2048
#define Dn 256
#define Kn 8

#define TS2 128          // t-chunks per batch row for pass2
#define TCH2 (Tn / TS2)  // 16

#define KBD ((size_t)Kn * Bn * Dn)   // 32768
#define NG  8                         // tc reduction groups

__device__ __forceinline__ float fexp2(float x) {
#if __has_builtin(__builtin_amdgcn_exp2f)
    return __builtin_amdgcn_exp2f(x);
#else
    return exp2f(x);
#endif
}
__device__ __forceinline__ float frcp(float x) {
#if __has_builtin(__builtin_amdgcn_rcpf)
    return __builtin_amdgcn_rcpf(x);
#else
    return 1.0f / x;
#endif
}

// exp(-0.5 (x-m)^2/(softplus(v)+eps)) = exp2(A x^2 + B x + G)
__device__ __forceinline__ void load_coefs(
    const float* __restrict__ Mean, const float* __restrict__ Var, int d,
    float* Ak, float* Bk, float* Gk)
{
    const float L2E = 1.4426950408889634f;
#pragma unroll
    for (int k = 0; k < Kn; ++k) {
        float m  = Mean[k * Dn + d];
        float v  = Var[k * Dn + d];
        float sp = logf(1.0f + expf(v));          // softplus
        float c2 = -0.5f * L2E / (sp + EPS);
        Ak[k] = c2;
        Bk[k] = -2.0f * c2 * m;
        Gk[k] = c2 * m * m;
    }
}

// Pass 1: per-block partials (no atomics):
//   P0[tc,k,b,d]=sum_t tau ; P1=sum_t tau*x ; P3=sum_t tau^3*x^2
template<int TCHT>
__global__ __launch_bounds__(256) void ucb_pass1(
    const float* __restrict__ X,
    const float* __restrict__ Mean, const float* __restrict__ Var,
    float* __restrict__ P0, float* __restrict__ P1, float* __restrict__ P3)
{
    const int d  = threadIdx.x;          // 0..255 (= Dn)
    const int tc = blockIdx.x;           // t-chunk
    const int b  = blockIdx.y;           // batch

    float Ak[Kn], Bk[Kn], Gk[Kn];
    load_coefs(Mean, Var, d, Ak, Bk, Gk);

    float s0[Kn], s1[Kn], s3[Kn];
#pragma unroll
    for (int k = 0; k < Kn; ++k) { s0[k] = 0.f; s1[k] = 0.f; s3[k] = 0.f; }

    const float* xp = X + ((size_t)b * Tn + (size_t)tc * TCHT) * Dn + d;
#pragma unroll 4
    for (int t = 0; t < TCHT; ++t) {
        float xv = xp[(size_t)t * Dn];
        float p[Kn];
        float sum = EPS;
#pragma unroll
        for (int k = 0; k < Kn; ++k) {
            float arg = fmaf(fmaf(Ak[k], xv, Bk[k]), xv, Gk[k]);
            p[k] = fexp2(arg);
            sum += p[k];
        }
        float q    = frcp(sum);
        float xq   = xv * q;
        float q2   = q * q;
        float xxq3 = (xv * xv) * (q2 * q);
#pragma unroll
        for (int k = 0; k < Kn; ++k) {
            float pk = p[k];
            float p3 = pk * pk * pk;
            s0[k] = fmaf(pk, q,    s0[k]);
            s1[k] = fmaf(pk, xq,   s1[k]);
            s3[k] = fmaf(p3, xxq3, s3[k]);
        }
    }

#pragma unroll
    for (int k = 0; k < Kn; ++k) {
        size_t o = (size_t)tc * KBD + ((size_t)(k * Bn + b) << 8) + d;
        P0[o] = s0[k];
        P1[o] = s1[k];
        P3[o] = s3[k];
    }
}

// Reduce stage A: Q[arr, g, idx] = sum over tcs in group g of P[arr][tc][idx]
__global__ __launch_bounds__(256) void ucb_reduceA(
    const float* __restrict__ P, float* __restrict__ Q, int ts1)
{
    const size_t idx = (size_t)blockIdx.x * 256 + threadIdx.x;  // over KBD
    const int arr = blockIdx.y;      // 0..2
    const int g   = blockIdx.z;      // 0..NG-1
    const int per = ts1 / NG;

    const float* p = P + ((size_t)arr * ts1 + (size_t)g * per) * KBD + idx;
    float a = 0.f;
#pragma unroll 4
    for (int i = 0; i < per; ++i)
        a += p[(size_t)i * KBD];
    Q[((size_t)(arr * NG + g)) * KBD + idx] = a;
}

// Mid: per (k,b,d): S = eps + sum_{b2,g} Q0 ; A1/A3 = sum_g Q1/Q3 ; -> R, RE
__global__ __launch_bounds__(256) void ucb_mid(
    const float* __restrict__ Q,
    float* __restrict__ R, float* __restrict__ RE)
{
    const size_t idx = (size_t)blockIdx.x * 256 + threadIdx.x;  // over KBD
    const int k = (int)(idx >> 12);          // / (Bn*Dn)
    const int d = (int)(idx & (Dn - 1));

    float s = EPS;
#pragma unroll
    for (int g = 0; g < NG; ++g) {
        const float* q0 = Q + (size_t)g * KBD + ((size_t)k << 12) + d;
#pragma unroll
        for (int b2 = 0; b2 < Bn; ++b2)
            s += q0[(size_t)b2 << 8];
    }
    float iS = frcp(s);

    float a1 = 0.f, a3 = 0.f;
#pragma unroll
    for (int g = 0; g < NG; ++g) {
        a1 += Q[((size_t)(NG + g))     * KBD + idx];
        a3 += Q[((size_t)(2 * NG + g)) * KBD + idx];
    }

    const float rs = rsqrtf(1.0f + EPS);     // 1/sqrt(pri+eps), pri==1
    float E  = a1 * iS * (1.0f / Tn);
    float V  = a3 * iS * iS * iS * (1.0f / Tn);
    float r  = rs * rsqrtf(V + EPS);
    R[idx]  = r;
    RE[idx] = r * E;
}

// Pass 2: out = (1/(sum_p+eps)) * sum_k p_k * (Rk*x - REk)
__global__ __launch_bounds__(256) void ucb_pass2(
    const float* __restrict__ X,
    const float* __restrict__ Mean, const float* __restrict__ Var,
    const float* __restrict__ R, const float* __restrict__ RE,
    float* __restrict__ Out)
{
    const int d  = threadIdx.x;
    const int tc = blockIdx.x;
    const int b  = blockIdx.y;

    float Ak[Kn], Bk[Kn], Gk[Kn];
    load_coefs(Mean, Var, d, Ak, Bk, Gk);

    float Rk[Kn], REk[Kn];
#pragma unroll
    for (int k = 0; k < Kn; ++k) {
        size_t idx = ((size_t)k * Bn + b) * Dn + d;
        Rk[k]  = R[idx];
        REk[k] = RE[idx];
    }

    const size_t base = ((size_t)b * Tn + (size_t)tc * TCH2) * Dn + d;
#pragma unroll 4
    for (int t = 0; t < TCH2; ++t) {
        float xv = X[base + (size_t)t * Dn];
        float p[Kn];
        float sum = EPS;
#pragma unroll
        for (int k = 0; k < Kn; ++k) {
            float arg = fmaf(fmaf(Ak[k], xv, Bk[k]), xv, Gk[k]);
            p[k] = fexp2(arg);
            sum += p[k];
        }
        float inv = frcp(sum);
        float acc = 0.f;
#pragma unroll
        for (int k = 0; k < Kn; ++k) {
            acc = fmaf(p[k], fmaf(Rk[k], xv, -REk[k]), acc);
        }
        Out[base + (size_t)t * Dn] = acc * inv;
    }
}

extern "C" void kernel_launch(void* const* d_in, const int* in_sizes, int n_in,
                              void* d_out, int out_size, void* d_ws, size_t ws_size,
                              hipStream_t stream)
{
    const float* x    = (const float*)d_in[0];
    const float* mean = (const float*)d_in[1];
    const float* var  = (const float*)d_in[2];
    // d_in[3] (prior): softmax over singleton axis == 1 -> compile-time rsqrt(1+eps)

    // ws: P (3*ts1*KBD) + Q (3*NG*KBD) + R,RE (2*KBD)
    int ts1 = 128;
    while (ts1 > NG) {
        size_t need = (3 * (size_t)ts1 * KBD + 3 * NG * KBD + 2 * KBD) * sizeof(float);
        if (need <= ws_size) break;
        ts1 >>= 1;
    }

    float* P0 = (float*)d_ws;
    float* P1 = P0 + (size_t)ts1 * KBD;
    float* P3 = P1 + (size_t)ts1 * KBD;
    float* Q  = P3 + (size_t)ts1 * KBD;     // 3*NG*KBD
    float* R  = Q  + 3 * NG * KBD;
    float* RE = R  + KBD;

    dim3 g1(ts1, Bn), blk(256);
    switch (Tn / ts1) {
        case 16:  ucb_pass1<16> <<<g1, blk, 0, stream>>>(x, mean, var, P0, P1, P3); break;
        case 32:  ucb_pass1<32> <<<g1, blk, 0, stream>>>(x, mean, var, P0, P1, P3); break;
        case 64:  ucb_pass1<64> <<<g1, blk, 0, stream>>>(x, mean, var, P0, P1, P3); break;
        case 128: ucb_pass1<128><<<g1, blk, 0, stream>>>(x, mean, var, P0, P1, P3); break;
        default:  ucb_pass1<256><<<g1, blk, 0, stream>>>(x, mean, var, P0, P1, P3); break;
    }

    ucb_reduceA<<<dim3(KBD / 256, 3, NG), dim3(256), 0, stream>>>(P0, Q, ts1);

    ucb_mid<<<dim3(KBD / 256), dim3(256), 0, stream>>>(Q, R, RE);

    ucb_pass2<<<dim3(TS2, Bn), dim3(256), 0, stream>>>(x, mean, var, R, RE, (float*)d_out);
}

// Round 8
// 57.291 us; speedup vs baseline: 5.2399x; 1.6578x over previous
//
#include <hip/hip_runtime.h>

#define EPS 1e-3f
#define Bn 16
#define Tn 2048
#define Dn 256
#define Kn 8

#define TS2 64           // t-chunks per batch row for pass2
#define TCH2 (Tn / TS2)  // 32

#define KBD ((size_t)Kn * Bn * Dn)   // 32768

__device__ __forceinline__ float fexp2(float x) {
#if __has_builtin(__builtin_amdgcn_exp2f)
    return __builtin_amdgcn_exp2f(x);
#else
    return exp2f(x);
#endif
}
__device__ __forceinline__ float frcp(float x) {
#if __has_builtin(__builtin_amdgcn_rcpf)
    return __builtin_amdgcn_rcpf(x);
#else
    return 1.0f / x;
#endif
}

// exp(-0.5 (x-m)^2/(softplus(v)+eps)) = exp2(A x^2 + B x + G)
__device__ __forceinline__ void load_coefs(
    const float* __restrict__ Mean, const float* __restrict__ Var, int d,
    float* Ak, float* Bk, float* Gk)
{
    const float L2E = 1.4426950408889634f;
#pragma unroll
    for (int k = 0; k < Kn; ++k) {
        float m  = Mean[k * Dn + d];
        float v  = Var[k * Dn + d];
        float sp = logf(1.0f + expf(v));          // softplus
        float c2 = -0.5f * L2E / (sp + EPS);
        Ak[k] = c2;
        Bk[k] = -2.0f * c2 * m;
        Gk[k] = c2 * m * m;
    }
}

// Pass 1: per-block partials (no atomics):
//   P0[tc,k,b,d]=sum_t tau ; P1=sum_t tau*x ; P3=sum_t tau^3*x^2
template<int TCHT>
__global__ __launch_bounds__(256) void ucb_pass1(
    const float* __restrict__ X,
    const float* __restrict__ Mean, const float* __restrict__ Var,
    float* __restrict__ P0, float* __restrict__ P1, float* __restrict__ P3)
{
    const int d  = threadIdx.x;          // 0..255 (= Dn)
    const int tc = blockIdx.x;           // t-chunk
    const int b  = blockIdx.y;           // batch

    float Ak[Kn], Bk[Kn], Gk[Kn];
    load_coefs(Mean, Var, d, Ak, Bk, Gk);

    float s0[Kn], s1[Kn], s3[Kn];
#pragma unroll
    for (int k = 0; k < Kn; ++k) { s0[k] = 0.f; s1[k] = 0.f; s3[k] = 0.f; }

    const float* xp = X + ((size_t)b * Tn + (size_t)tc * TCHT) * Dn + d;
#pragma unroll 4
    for (int t = 0; t < TCHT; ++t) {
        float xv = xp[(size_t)t * Dn];
        float p[Kn];
        float sum = EPS;
#pragma unroll
        for (int k = 0; k < Kn; ++k) {
            float arg = fmaf(fmaf(Ak[k], xv, Bk[k]), xv, Gk[k]);
            p[k] = fexp2(arg);
            sum += p[k];
        }
        float q    = frcp(sum);
        float xq   = xv * q;
        float q2   = q * q;
        float xxq3 = (xv * xv) * (q2 * q);
#pragma unroll
        for (int k = 0; k < Kn; ++k) {
            float pk = p[k];
            float p3 = pk * pk * pk;
            s0[k] = fmaf(pk, q,    s0[k]);
            s1[k] = fmaf(pk, xq,   s1[k]);
            s3[k] = fmaf(p3, xxq3, s3[k]);
        }
    }

#pragma unroll
    for (int k = 0; k < Kn; ++k) {
        size_t o = (size_t)tc * KBD + ((size_t)(k * Bn + b) << 8) + d;
        P0[o] = s0[k];
        P1[o] = s1[k];
        P3[o] = s3[k];
    }
}

// Reduce: Q[arr][idx] = sum_tc P[arr][tc][idx]   (384 blocks)
__global__ __launch_bounds__(256) void ucb_reduce(
    const float* __restrict__ P, float* __restrict__ Q, int ts1)
{
    const size_t idx = (size_t)blockIdx.x * 256 + threadIdx.x;  // over KBD
    const int arr = blockIdx.y;      // 0..2

    const float* p = P + (size_t)arr * ts1 * KBD + idx;
    float a = 0.f;
#pragma unroll 8
    for (int t = 0; t < ts1; ++t)
        a += p[(size_t)t * KBD];
    Q[(size_t)arr * KBD + idx] = a;
}

// Pass 2: inline mid (S,R,E from Q) + output
//   out = (1/(sum_p+eps)) * sum_k p_k * (Rk*x - Ek)
__global__ __launch_bounds__(256) void ucb_pass2(
    const float* __restrict__ X,
    const float* __restrict__ Mean, const float* __restrict__ Var,
    const float* __restrict__ Q,
    float* __restrict__ Out)
{
    const int d  = threadIdx.x;
    const int tc = blockIdx.x;
    const int b  = blockIdx.y;

    float Ak[Kn], Bk[Kn], Gk[Kn];
    load_coefs(Mean, Var, d, Ak, Bk, Gk);

    // inline "mid": S[k,d] = eps + sum_b Q0 ; E,V,R from Q1,Q3
    const float rs = rsqrtf(1.0f + EPS);     // 1/sqrt(pri+eps), pri==1
    float Rk[Kn], Ek[Kn];
#pragma unroll
    for (int k = 0; k < Kn; ++k) {
        const float* q0 = Q + ((size_t)k << 12) + d;   // Q0[k,*,d]
        float s = EPS;
#pragma unroll
        for (int b2 = 0; b2 < Bn; ++b2)
            s += q0[(size_t)b2 << 8];
        float iS = frcp(s);

        size_t idx = ((size_t)(k * Bn + b) << 8) + d;
        float a1 = Q[KBD + idx];
        float a3 = Q[2 * KBD + idx];
        float E  = a1 * iS * (1.0f / Tn);
        float V  = a3 * (iS * iS * iS) * (1.0f / Tn);
        float r  = rs * rsqrtf(V + EPS);
        Rk[k] = r;
        Ek[k] = r * E;
    }

    const size_t base = ((size_t)b * Tn + (size_t)tc * TCH2) * Dn + d;
#pragma unroll 4
    for (int t = 0; t < TCH2; ++t) {
        float xv = X[base + (size_t)t * Dn];
        float p[Kn];
        float sum = EPS;
#pragma unroll
        for (int k = 0; k < Kn; ++k) {
            float arg = fmaf(fmaf(Ak[k], xv, Bk[k]), xv, Gk[k]);
            p[k] = fexp2(arg);
            sum += p[k];
        }
        float inv = frcp(sum);
        float acc = 0.f;
#pragma unroll
        for (int k = 0; k < Kn; ++k) {
            acc = fmaf(p[k], fmaf(Rk[k], xv, -Ek[k]), acc);
        }
        Out[base + (size_t)t * Dn] = acc * inv;
    }
}

extern "C" void kernel_launch(void* const* d_in, const int* in_sizes, int n_in,
                              void* d_out, int out_size, void* d_ws, size_t ws_size,
                              hipStream_t stream)
{
    const float* x    = (const float*)d_in[0];
    const float* mean = (const float*)d_in[1];
    const float* var  = (const float*)d_in[2];
    // d_in[3] (prior): softmax over singleton axis == 1 -> compile-time rsqrt(1+eps)

    // ws: P (3*ts1*KBD) + Q (3*KBD)
    int ts1 = 64;
    while (ts1 > 4) {
        size_t need = (3 * (size_t)ts1 * KBD + 3 * KBD) * sizeof(float);
        if (need <= ws_size) break;
        ts1 >>= 1;
    }

    float* P = (float*)d_ws;                 // 3*ts1*KBD
    float* Q = P + 3 * (size_t)ts1 * KBD;    // 3*KBD

    dim3 g1(ts1, Bn), blk(256);
    switch (Tn / ts1) {
        case 32:  ucb_pass1<32> <<<g1, blk, 0, stream>>>(x, mean, var,
                      P, P + (size_t)ts1 * KBD, P + 2 * (size_t)ts1 * KBD); break;
        case 64:  ucb_pass1<64> <<<g1, blk, 0, stream>>>(x, mean, var,
                      P, P + (size_t)ts1 * KBD, P + 2 * (size_t)ts1 * KBD); break;
        case 128: ucb_pass1<128><<<g1, blk, 0, stream>>>(x, mean, var,
                      P, P + (size_t)ts1 * KBD, P + 2 * (size_t)ts1 * KBD); break;
        default:  ucb_pass1<512><<<g1, blk, 0, stream>>>(x, mean, var,
                      P, P + (size_t)ts1 * KBD, P + 2 * (size_t)ts1 * KBD); break;
    }

    ucb_reduce<<<dim3(KBD / 256, 3), dim3(256), 0, stream>>>(P, Q, ts1);

    ucb_pass2<<<dim3(TS2, Bn), dim3(256), 0, stream>>>(x, mean, var, Q, (float*)d_out);
}